// Round 14
// baseline (509.527 us; speedup 1.0000x reference)
//
#include <hip/hip_runtime.h>
#include <hip/hip_bf16.h>

#define BATCH 64
#define SEQT  512
#define EMB   1024
#define HID   2048
#define VOC   32000

using bf16x8 = __attribute__((ext_vector_type(8))) __bf16;
using f32x4  = __attribute__((ext_vector_type(4))) float;

__device__ __forceinline__ void split2(float x, __bf16& hi, __bf16& lo) {
  hi = (__bf16)x;
  lo = (__bf16)(x - (float)hi);
}

// ---------------------------------------------------------------------------
// Layer kernel (round-9 verbatim, passing): h_out = tanh(A @ W + bias),
// split-bf16 (3 MFMA products), 16x16x32 MFMA, 256 blocks x 16 waves,
// LDS reduce. PACKOUT epilogue emits f16x2 hp[kp][64m] + f32 hf[k][64m].
// ---------------------------------------------------------------------------
template <int KTOT, bool GATHER, bool PACKOUT>
__global__ __launch_bounds__(1024) void layer_kernel(
    const int* __restrict__ X, const float* __restrict__ emb,
    const __hip_bfloat16* __restrict__ hin_hi,
    const __hip_bfloat16* __restrict__ hin_lo,
    const float* __restrict__ W, const float* __restrict__ bias,
    __hip_bfloat16* __restrict__ hout_hi,
    __hip_bfloat16* __restrict__ hout_lo,
    unsigned* __restrict__ hp, float* __restrict__ hf) {
  constexpr int KCHUNK = KTOT / 16;   // 128 (HID) / 64 (EMB)
  constexpr int KSTEPS = KCHUNK / 32; // 4 / 2
  __shared__ float red[16 * 16 * 40];  // [wave][n][m_local pad 32->40]

  const int tid = threadIdx.x;
  const int w = tid >> 6;
  const int l = tid & 63;
  const int ln = l & 15;
  const int lg = l >> 4;
  const int n0 = (blockIdx.x & 127) * 16;
  const int mb = (blockIdx.x >> 7) * 32;  // M-half base

  f32x4 acc[2];
#pragma unroll
  for (int mt = 0; mt < 2; ++mt) acc[mt] = f32x4{0.f, 0.f, 0.f, 0.f};

  const float* grow[2];
#pragma unroll
  for (int mt = 0; mt < 2; ++mt) {
    if constexpr (GATHER) {
      const int m = mb + ln + 16 * mt;
      const int tok = X[m * SEQT + (SEQT - 1)];
      grow[mt] = emb + (size_t)tok * EMB;
    } else {
      grow[mt] = nullptr;
    }
  }

  const int kwave = w * KCHUNK + lg * 8;
  const float* Wc = W + n0 + ln;

  // hoist ALL W loads for this wave's K-chunk
  float wv[KSTEPS * 8];
#pragma unroll
  for (int j = 0; j < KSTEPS * 8; ++j)
    wv[j] = Wc[(size_t)(kwave + (j >> 3) * 32 + (j & 7)) * HID];

  // hoist ALL A fragments (split-bf16 planes)
  bf16x8 Ah[2][KSTEPS], Al[2][KSTEPS];
  if constexpr (GATHER) {
#pragma unroll
    for (int mt = 0; mt < 2; ++mt)
#pragma unroll
      for (int ks = 0; ks < KSTEPS; ++ks) {
        const float* p = grow[mt] + kwave + ks * 32;
        const f32x4 v0 = *reinterpret_cast<const f32x4*>(p);
        const f32x4 v1 = *reinterpret_cast<const f32x4*>(p + 4);
#pragma unroll
        for (int i = 0; i < 4; ++i) {
          __bf16 h_, l_;
          split2(v0[i], h_, l_);
          Ah[mt][ks][i] = h_;
          Al[mt][ks][i] = l_;
          split2(v1[i], h_, l_);
          Ah[mt][ks][4 + i] = h_;
          Al[mt][ks][4 + i] = l_;
        }
      }
  } else {
#pragma unroll
    for (int mt = 0; mt < 2; ++mt)
#pragma unroll
      for (int ks = 0; ks < KSTEPS; ++ks) {
        const size_t off = (size_t)(mb + ln + 16 * mt) * KTOT + kwave + ks * 32;
        Ah[mt][ks] = *reinterpret_cast<const bf16x8*>(hin_hi + off);
        Al[mt][ks] = *reinterpret_cast<const bf16x8*>(hin_lo + off);
      }
  }

#pragma unroll
  for (int ks = 0; ks < KSTEPS; ++ks) {
    bf16x8 bhi, blo;
#pragma unroll
    for (int i = 0; i < 8; ++i) {
      __bf16 h_, l_;
      split2(wv[ks * 8 + i], h_, l_);
      bhi[i] = h_;
      blo[i] = l_;
    }
#pragma unroll
    for (int mt = 0; mt < 2; ++mt) {
      acc[mt] = __builtin_amdgcn_mfma_f32_16x16x32_bf16(Ah[mt][ks], bhi, acc[mt], 0, 0, 0);
      acc[mt] = __builtin_amdgcn_mfma_f32_16x16x32_bf16(Al[mt][ks], bhi, acc[mt], 0, 0, 0);
      acc[mt] = __builtin_amdgcn_mfma_f32_16x16x32_bf16(Ah[mt][ks], blo, acc[mt], 0, 0, 0);
    }
  }

  // stash: red[(w*16+n)*40 + m_local]; acc[mt][j] -> m_local = mt*16+lg*4+j
  float* dst = &red[(w * 16 + ln) * 40 + lg * 4];
#pragma unroll
  for (int mt = 0; mt < 2; ++mt)
    *reinterpret_cast<f32x4*>(dst + mt * 16) = acc[mt];

  __syncthreads();

  if (tid < 512) {
    const int m = tid >> 4, n = tid & 15;  // m_local 0..31
    float s = 0.f;
#pragma unroll
    for (int ww = 0; ww < 16; ++ww) s += red[(ww * 16 + n) * 40 + m];
    s += bias[n0 + n];
    const float hval = tanhf(s);
    if constexpr (PACKOUT) {
      // pack adjacent n-columns (k-index c = n0+n) into f16x2; also f32 copy
      const int c = n0 + n;
      const int mg = mb + m;
      hf[(size_t)c * 64 + mg] = hval;
      const float partner = __shfl_xor(hval, 1, 64);
      if ((tid & 1) == 0) {
        using fp2 = __attribute__((ext_vector_type(2))) __fp16;
        const fp2 pk = __builtin_amdgcn_cvt_pkrtz(hval, partner);
        hp[(size_t)(c >> 1) * 64 + mg] = __builtin_bit_cast(unsigned, pk);
      }
    } else {
      __bf16 h_, l_;
      split2(hval, h_, l_);
      const size_t off = (size_t)(mb + m) * HID + (n0 + n);
      hout_hi[off] = *reinterpret_cast<__hip_bfloat16*>(&h_);
      hout_lo[off] = *reinterpret_cast<__hip_bfloat16*>(&l_);
    }
  }
}

// ---------------------------------------------------------------------------
// out_fused: out[64][VOC] = h @ W_hy + b_y, single kernel (no scratch,
// no reduce launch). INNER LOOP IS ROUND-9-PROVEN VERBATIM: per-lane
// n-column W stream (4-row chunks, 4-buffer nontemporal pipeline) +
// wave-uniform hp reads over all 64 m. Only the K-split moved: wave w
// owns kp-quarter [w*256,(w+1)*256) of the SAME 64-n tile; partials
// combined via the layer-kernel-proven LDS reduce (write red[w][m][lane],
// read summed over w -- conflict-free both ways), bias, direct store.
// r10/11/13 restructures (LDS feed / m-split) all failed with identical
// absmax=316 -- those structures are retired; this touches neither.
// Grid: 500 blocks (64-col tiles) x 256 thr (4 waves); 64 KB LDS, 2/CU.
// ---------------------------------------------------------------------------
__global__ __launch_bounds__(256) void out_fused(
    const unsigned* __restrict__ hp, const float* __restrict__ hf,
    const float* __restrict__ Why, const float* __restrict__ by,
    float* __restrict__ out) {
  constexpr int KPW = (HID / 2) / 4;  // 256 k-pairs per wave
  constexpr int NCH = KPW / 2;        // 128 chunks of 2 kp (4 k-rows)
  __shared__ float red[4 * 64 * 64];  // [wave][m][lane-n] 64 KB

  const int tid = threadIdx.x;
  const int wq = tid >> 6;
  const int nl = tid & 63;
  const int n0 = blockIdx.x * 64;
  const int n = n0 + nl;
  const int kp0 = wq * KPW;

  float acc[64];
#pragma unroll
  for (int m = 0; m < 64; ++m) acc[m] = 0.f;

  const float* W0 = Why + n;

#if __has_builtin(__builtin_amdgcn_fdot2)
  using h2  = __attribute__((ext_vector_type(2))) _Float16;
  using fp2 = __attribute__((ext_vector_type(2))) __fp16;

#define LOADC(c_, buf_)                                                      \
  {                                                                          \
    const int cc_ = (c_) & (NCH - 1);                                        \
    const size_t kb_ = (size_t)(kp0 + 2 * cc_) * 2;                          \
    buf_[0] = __builtin_nontemporal_load(W0 + (kb_ + 0) * VOC);              \
    buf_[1] = __builtin_nontemporal_load(W0 + (kb_ + 1) * VOC);              \
    buf_[2] = __builtin_nontemporal_load(W0 + (kb_ + 2) * VOC);              \
    buf_[3] = __builtin_nontemporal_load(W0 + (kb_ + 3) * VOC);              \
  }

#define COMPC(c_, buf_)                                                      \
  {                                                                          \
    _Pragma("unroll") for (int j_ = 0; j_ < 2; ++j_) {                       \
      const int kp_ = kp0 + 2 * (c_) + j_;                                   \
      const fp2 raw_ =                                                       \
          __builtin_amdgcn_cvt_pkrtz(buf_[2 * j_], buf_[2 * j_ + 1]);        \
      const h2 wp_ = __builtin_bit_cast(h2, raw_);                           \
      const unsigned* hk_ = hp + (size_t)kp_ * 64;                           \
      _Pragma("unroll") for (int m_ = 0; m_ < 64; ++m_) {                    \
        acc[m_] = __builtin_amdgcn_fdot2(                                    \
            wp_, __builtin_bit_cast(h2, hk_[m_]), acc[m_], false);           \
      }                                                                      \
    }                                                                        \
  }

  float bA[4], bB[4], bC[4], bD[4];
  LOADC(0, bA);
  LOADC(1, bB);
  LOADC(2, bC);
  LOADC(3, bD);
#pragma unroll 1
  for (int c = 0; c < NCH; c += 4) {
    COMPC(c + 0, bA);
    LOADC(c + 4, bA);
    COMPC(c + 1, bB);
    LOADC(c + 5, bB);
    COMPC(c + 2, bC);
    LOADC(c + 6, bC);
    COMPC(c + 3, bD);
    LOADC(c + 7, bD);
  }
#undef COMPC
#undef LOADC
#else
  const int k0 = wq * (HID / 4);
#pragma unroll 2
  for (int k = k0; k < k0 + HID / 4; ++k) {
    const float wvv = __builtin_nontemporal_load(W0 + (size_t)k * VOC);
    const float* hk = hf + (size_t)k * 64;
#pragma unroll
    for (int m = 0; m < 64; ++m) acc[m] = fmaf(wvv, hk[m], acc[m]);
  }
#endif

  // LDS reduce across the 4 waves: red[(wq*64 + m)*64 + nl]
  {
    float* dst = &red[(size_t)wq * 64 * 64 + nl];
#pragma unroll
    for (int m = 0; m < 64; ++m) dst[m * 64] = acc[m];
  }
  __syncthreads();

  // 4096 outputs (64 m x 64 n), 256 threads -> 16 each, coalesced in n
#pragma unroll
  for (int r = 0; r < 16; ++r) {
    const int o = tid + r * 256;
    const int m = o >> 6, n2 = o & 63;
    float s = by[n0 + n2];
#pragma unroll
    for (int ww = 0; ww < 4; ++ww) s += red[(ww * 64 + m) * 64 + n2];
    __builtin_nontemporal_store(s, out + (size_t)m * VOC + (n0 + n2));
  }
}

extern "C" void kernel_launch(void* const* d_in, const int* in_sizes, int n_in,
                              void* d_out, int out_size, void* d_ws,
                              size_t ws_size, hipStream_t stream) {
  const int* X = (const int*)d_in[0];
  const float* emb = (const float*)d_in[1];
  const float* W_xh = (const float*)d_in[2];
  const float* W_hh = (const float*)d_in[3];
  const float* W_hy = (const float*)d_in[4];
  const float* b_h = (const float*)d_in[5];
  const float* b_y = (const float*)d_in[6];
  float* out = (float*)d_out;

  char* ws = (char*)d_ws;
  const size_t PLANE = (size_t)BATCH * HID;  // elements
  __hip_bfloat16* hA_hi = (__hip_bfloat16*)ws;
  __hip_bfloat16* hA_lo = hA_hi + PLANE;
  __hip_bfloat16* hB_hi = hA_lo + PLANE;
  __hip_bfloat16* hB_lo = hB_hi + PLANE;
  char* p = ws + 4 * PLANE * sizeof(__hip_bfloat16);
  unsigned* hp = (unsigned*)p;                 // 1024 kp x 64 m u32
  p += (size_t)(HID / 2) * BATCH * sizeof(unsigned);
  float* hf = (float*)p;                       // 2048 k x 64 m f32

  dim3 blk(1024), grd(256);
  layer_kernel<EMB, true, false><<<grd, blk, 0, stream>>>(
      X, emb, nullptr, nullptr, W_xh, b_h, hA_hi, hA_lo, nullptr, nullptr);
  layer_kernel<HID, false, false><<<grd, blk, 0, stream>>>(
      nullptr, nullptr, hA_hi, hA_lo, W_hh, b_h, hB_hi, hB_lo, nullptr, nullptr);
  layer_kernel<HID, false, false><<<grd, blk, 0, stream>>>(
      nullptr, nullptr, hB_hi, hB_lo, W_hh, b_h, hA_hi, hA_lo, nullptr, nullptr);
  layer_kernel<HID, false, false><<<grd, blk, 0, stream>>>(
      nullptr, nullptr, hA_hi, hA_lo, W_hh, b_h, hB_hi, hB_lo, nullptr, nullptr);
  layer_kernel<HID, false, true><<<grd, blk, 0, stream>>>(
      nullptr, nullptr, hB_hi, hB_lo, W_hh, b_h, nullptr, nullptr, hp, hf);

  out_fused<<<dim3(500), dim3(256), 0, stream>>>(hp, hf, W_hy, b_y, out);
}

// Round 15
// 167.693 us; speedup vs baseline: 3.0385x; 3.0385x over previous
//
#include <hip/hip_runtime.h>
#include <hip/hip_bf16.h>

#define BATCH 64
#define SEQT  512
#define EMB   1024
#define HID   2048
#define VOC   32000
#define KSPLIT 8

using bf16x8 = __attribute__((ext_vector_type(8))) __bf16;
using f32x4  = __attribute__((ext_vector_type(4))) float;
using f32x2  = __attribute__((ext_vector_type(2))) float;

__device__ __forceinline__ void split2(float x, __bf16& hi, __bf16& lo) {
  hi = (__bf16)x;
  lo = (__bf16)(x - (float)hi);
}

// ---------------------------------------------------------------------------
// Layer kernel (round-9 verbatim, passing): h_out = tanh(A @ W + bias),
// split-bf16 (3 MFMA products), 16x16x32 MFMA, 256 blocks x 16 waves,
// LDS reduce. PACKOUT epilogue emits f16x2 hp[kp][64m] + f32 hf[k][64m].
// ---------------------------------------------------------------------------
template <int KTOT, bool GATHER, bool PACKOUT>
__global__ __launch_bounds__(1024) void layer_kernel(
    const int* __restrict__ X, const float* __restrict__ emb,
    const __hip_bfloat16* __restrict__ hin_hi,
    const __hip_bfloat16* __restrict__ hin_lo,
    const float* __restrict__ W, const float* __restrict__ bias,
    __hip_bfloat16* __restrict__ hout_hi,
    __hip_bfloat16* __restrict__ hout_lo,
    unsigned* __restrict__ hp, float* __restrict__ hf) {
  constexpr int KCHUNK = KTOT / 16;   // 128 (HID) / 64 (EMB)
  constexpr int KSTEPS = KCHUNK / 32; // 4 / 2
  __shared__ float red[16 * 16 * 40];  // [wave][n][m_local pad 32->40]

  const int tid = threadIdx.x;
  const int w = tid >> 6;
  const int l = tid & 63;
  const int ln = l & 15;
  const int lg = l >> 4;
  const int n0 = (blockIdx.x & 127) * 16;
  const int mb = (blockIdx.x >> 7) * 32;  // M-half base

  f32x4 acc[2];
#pragma unroll
  for (int mt = 0; mt < 2; ++mt) acc[mt] = f32x4{0.f, 0.f, 0.f, 0.f};

  const float* grow[2];
#pragma unroll
  for (int mt = 0; mt < 2; ++mt) {
    if constexpr (GATHER) {
      const int m = mb + ln + 16 * mt;
      const int tok = X[m * SEQT + (SEQT - 1)];
      grow[mt] = emb + (size_t)tok * EMB;
    } else {
      grow[mt] = nullptr;
    }
  }

  const int kwave = w * KCHUNK + lg * 8;
  const float* Wc = W + n0 + ln;

  // hoist ALL W loads for this wave's K-chunk
  float wv[KSTEPS * 8];
#pragma unroll
  for (int j = 0; j < KSTEPS * 8; ++j)
    wv[j] = Wc[(size_t)(kwave + (j >> 3) * 32 + (j & 7)) * HID];

  // hoist ALL A fragments (split-bf16 planes)
  bf16x8 Ah[2][KSTEPS], Al[2][KSTEPS];
  if constexpr (GATHER) {
#pragma unroll
    for (int mt = 0; mt < 2; ++mt)
#pragma unroll
      for (int ks = 0; ks < KSTEPS; ++ks) {
        const float* p = grow[mt] + kwave + ks * 32;
        const f32x4 v0 = *reinterpret_cast<const f32x4*>(p);
        const f32x4 v1 = *reinterpret_cast<const f32x4*>(p + 4);
#pragma unroll
        for (int i = 0; i < 4; ++i) {
          __bf16 h_, l_;
          split2(v0[i], h_, l_);
          Ah[mt][ks][i] = h_;
          Al[mt][ks][i] = l_;
          split2(v1[i], h_, l_);
          Ah[mt][ks][4 + i] = h_;
          Al[mt][ks][4 + i] = l_;
        }
      }
  } else {
#pragma unroll
    for (int mt = 0; mt < 2; ++mt)
#pragma unroll
      for (int ks = 0; ks < KSTEPS; ++ks) {
        const size_t off = (size_t)(mb + ln + 16 * mt) * KTOT + kwave + ks * 32;
        Ah[mt][ks] = *reinterpret_cast<const bf16x8*>(hin_hi + off);
        Al[mt][ks] = *reinterpret_cast<const bf16x8*>(hin_lo + off);
      }
  }

#pragma unroll
  for (int ks = 0; ks < KSTEPS; ++ks) {
    bf16x8 bhi, blo;
#pragma unroll
    for (int i = 0; i < 8; ++i) {
      __bf16 h_, l_;
      split2(wv[ks * 8 + i], h_, l_);
      bhi[i] = h_;
      blo[i] = l_;
    }
#pragma unroll
    for (int mt = 0; mt < 2; ++mt) {
      acc[mt] = __builtin_amdgcn_mfma_f32_16x16x32_bf16(Ah[mt][ks], bhi, acc[mt], 0, 0, 0);
      acc[mt] = __builtin_amdgcn_mfma_f32_16x16x32_bf16(Al[mt][ks], bhi, acc[mt], 0, 0, 0);
      acc[mt] = __builtin_amdgcn_mfma_f32_16x16x32_bf16(Ah[mt][ks], blo, acc[mt], 0, 0, 0);
    }
  }

  // stash: red[(w*16+n)*40 + m_local]; acc[mt][j] -> m_local = mt*16+lg*4+j
  float* dst = &red[(w * 16 + ln) * 40 + lg * 4];
#pragma unroll
  for (int mt = 0; mt < 2; ++mt)
    *reinterpret_cast<f32x4*>(dst + mt * 16) = acc[mt];

  __syncthreads();

  if (tid < 512) {
    const int m = tid >> 4, n = tid & 15;  // m_local 0..31
    float s = 0.f;
#pragma unroll
    for (int ww = 0; ww < 16; ++ww) s += red[(ww * 16 + n) * 40 + m];
    s += bias[n0 + n];
    const float hval = tanhf(s);
    if constexpr (PACKOUT) {
      // pack adjacent n-columns (k-index c = n0+n) into f16x2; also f32 copy
      const int c = n0 + n;
      const int mg = mb + m;
      hf[(size_t)c * 64 + mg] = hval;
      const float partner = __shfl_xor(hval, 1, 64);
      if ((tid & 1) == 0) {
        using fp2 = __attribute__((ext_vector_type(2))) __fp16;
        const fp2 pk = __builtin_amdgcn_cvt_pkrtz(hval, partner);
        hp[(size_t)(c >> 1) * 64 + mg] = __builtin_bit_cast(unsigned, pk);
      }
    } else {
      __bf16 h_, l_;
      split2(hval, h_, l_);
      const size_t off = (size_t)(mb + m) * HID + (n0 + n);
      hout_hi[off] = *reinterpret_cast<__hip_bfloat16*>(&h_);
      hout_lo[off] = *reinterpret_cast<__hip_bfloat16*>(&l_);
    }
  }
}

// ---------------------------------------------------------------------------
// out_main v7 = r9 skeleton with n_t=2 (the h-feed arithmetic-intensity fix).
// Evidence base: r9 (s_load feed, n_t=1) ~125us; r12 (VMEM feed) 315us;
// r14 (split hp streams) 470us; all VALUBusy<20% -> h-feed-stall-bound.
// Per kp a wave needs 256 B of broadcast h; at n_t=1 it has 128 VALU cycles
// of cover, at n_t=2 it has 256 -> feed pressure halves, K$ lines get
// L2-latency cover with the depth-2 scalar prefetch the compiler already
// emits. W loads widen to float2 (512 B/wave). Same block-shared hp stream
// (all waves, same kp range -> K$ reuse), same 4-buffer W pipeline, plain
// scratch stores. Grid: 125 nt x KSPLIT(8) = 1000 blocks x 128 thr (2 waves).
// ---------------------------------------------------------------------------
__global__ __launch_bounds__(128, 2) void out_main(
    const unsigned* __restrict__ hp, const float* __restrict__ hf,
    const float* __restrict__ Why, float* __restrict__ scratch) {
  const int tid = threadIdx.x;
  const int nt = blockIdx.x % 125;
  const int kq = blockIdx.x / 125;
  const int n = nt * 256 + tid * 2;  // thread owns n, n+1

  f32x2 acc2[64];
#pragma unroll
  for (int m = 0; m < 64; ++m) acc2[m] = f32x2{0.f, 0.f};

  constexpr int KPB = HID / KSPLIT / 2;  // 128 k-pairs per block
  constexpr int NCH = KPB / 2;           // 64 chunks of 2 kp (4 k-rows)
  const int kp0 = kq * KPB;
  const float* W0 = Why + n;

#if __has_builtin(__builtin_amdgcn_fdot2)
  using h2  = __attribute__((ext_vector_type(2))) _Float16;
  using fp2 = __attribute__((ext_vector_type(2))) __fp16;

#define LOADC(c_, buf_)                                                      \
  {                                                                          \
    const int cc_ = (c_) & (NCH - 1);                                        \
    const size_t kb_ = (size_t)(kp0 + 2 * cc_) * 2;                          \
    buf_[0] = __builtin_nontemporal_load(                                    \
        reinterpret_cast<const f32x2*>(W0 + (kb_ + 0) * VOC));               \
    buf_[1] = __builtin_nontemporal_load(                                    \
        reinterpret_cast<const f32x2*>(W0 + (kb_ + 1) * VOC));               \
    buf_[2] = __builtin_nontemporal_load(                                    \
        reinterpret_cast<const f32x2*>(W0 + (kb_ + 2) * VOC));               \
    buf_[3] = __builtin_nontemporal_load(                                    \
        reinterpret_cast<const f32x2*>(W0 + (kb_ + 3) * VOC));               \
  }

#define COMPC(c_, buf_)                                                      \
  {                                                                          \
    _Pragma("unroll") for (int j_ = 0; j_ < 2; ++j_) {                       \
      const int kp_ = kp0 + 2 * (c_) + j_;                                   \
      const fp2 r0_ = __builtin_amdgcn_cvt_pkrtz(buf_[2 * j_][0],            \
                                                 buf_[2 * j_ + 1][0]);       \
      const fp2 r1_ = __builtin_amdgcn_cvt_pkrtz(buf_[2 * j_][1],            \
                                                 buf_[2 * j_ + 1][1]);       \
      const h2 wp0_ = __builtin_bit_cast(h2, r0_);                           \
      const h2 wp1_ = __builtin_bit_cast(h2, r1_);                           \
      const unsigned* hk_ = hp + (size_t)kp_ * 64;                           \
      _Pragma("unroll") for (int m_ = 0; m_ < 64; ++m_) {                    \
        const h2 hm_ = __builtin_bit_cast(h2, hk_[m_]);                      \
        acc2[m_][0] = __builtin_amdgcn_fdot2(wp0_, hm_, acc2[m_][0], false); \
        acc2[m_][1] = __builtin_amdgcn_fdot2(wp1_, hm_, acc2[m_][1], false); \
      }                                                                      \
    }                                                                        \
  }

  f32x2 bA[4], bB[4], bC[4], bD[4];
  LOADC(0, bA);
  LOADC(1, bB);
  LOADC(2, bC);
  LOADC(3, bD);
#pragma unroll 1
  for (int c = 0; c < NCH; c += 4) {
    COMPC(c + 0, bA);
    LOADC(c + 4, bA);
    COMPC(c + 1, bB);
    LOADC(c + 5, bB);
    COMPC(c + 2, bC);
    LOADC(c + 6, bC);
    COMPC(c + 3, bD);
    LOADC(c + 7, bD);
  }
#undef COMPC
#undef LOADC
#else
  const int k0 = kq * (HID / KSPLIT);
#pragma unroll 2
  for (int k = k0; k < k0 + HID / KSPLIT; ++k) {
    const f32x2 wvv = *reinterpret_cast<const f32x2*>(W0 + (size_t)k * VOC);
    const float* hk = hf + (size_t)k * 64;
#pragma unroll
    for (int m = 0; m < 64; ++m) {
      acc2[m][0] = fmaf(wvv[0], hk[m], acc2[m][0]);
      acc2[m][1] = fmaf(wvv[1], hk[m], acc2[m][1]);
    }
  }
#endif

  // PLAIN stores (kernel-to-kernel data must go through the normal L2 path)
  float* sc = scratch + (size_t)kq * ((size_t)BATCH * VOC) + n;
#pragma unroll
  for (int m = 0; m < 64; ++m)
    *reinterpret_cast<f32x2*>(sc + (size_t)m * VOC) = acc2[m];
}

// ---------------------------------------------------------------------------
// reduce_out: out[m][n] = sum_q scratch[q][m][n] + b_y[n].
// Grid (125, 64) x 256 thr; scratch is L2/L3-hot.
// ---------------------------------------------------------------------------
__global__ __launch_bounds__(256) void reduce_out(
    const float* __restrict__ scratch, const float* __restrict__ by,
    float* __restrict__ out) {
  const int n = blockIdx.x * 256 + threadIdx.x;
  const int m = blockIdx.y;
  float s = by[n];
#pragma unroll
  for (int q = 0; q < KSPLIT; ++q)
    s += scratch[(size_t)q * ((size_t)BATCH * VOC) + (size_t)m * VOC + n];
  __builtin_nontemporal_store(s, out + (size_t)m * VOC + n);
}

extern "C" void kernel_launch(void* const* d_in, const int* in_sizes, int n_in,
                              void* d_out, int out_size, void* d_ws,
                              size_t ws_size, hipStream_t stream) {
  const int* X = (const int*)d_in[0];
  const float* emb = (const float*)d_in[1];
  const float* W_xh = (const float*)d_in[2];
  const float* W_hh = (const float*)d_in[3];
  const float* W_hy = (const float*)d_in[4];
  const float* b_h = (const float*)d_in[5];
  const float* b_y = (const float*)d_in[6];
  float* out = (float*)d_out;

  char* ws = (char*)d_ws;
  const size_t PLANE = (size_t)BATCH * HID;  // elements
  __hip_bfloat16* hA_hi = (__hip_bfloat16*)ws;
  __hip_bfloat16* hA_lo = hA_hi + PLANE;
  __hip_bfloat16* hB_hi = hA_lo + PLANE;
  __hip_bfloat16* hB_lo = hB_hi + PLANE;
  char* p = ws + 4 * PLANE * sizeof(__hip_bfloat16);
  unsigned* hp = (unsigned*)p;                 // 1024 kp x 64 m u32
  p += (size_t)(HID / 2) * BATCH * sizeof(unsigned);
  float* hf = (float*)p;                       // 2048 k x 64 m f32
  p += (size_t)HID * BATCH * sizeof(float);
  float* scratch = (float*)p;                  // KSPLIT x 64 x 32000 f32

  dim3 blk(1024), grd(256);
  layer_kernel<EMB, true, false><<<grd, blk, 0, stream>>>(
      X, emb, nullptr, nullptr, W_xh, b_h, hA_hi, hA_lo, nullptr, nullptr);
  layer_kernel<HID, false, false><<<grd, blk, 0, stream>>>(
      nullptr, nullptr, hA_hi, hA_lo, W_hh, b_h, hB_hi, hB_lo, nullptr, nullptr);
  layer_kernel<HID, false, false><<<grd, blk, 0, stream>>>(
      nullptr, nullptr, hB_hi, hB_lo, W_hh, b_h, hA_hi, hA_lo, nullptr, nullptr);
  layer_kernel<HID, false, false><<<grd, blk, 0, stream>>>(
      nullptr, nullptr, hA_hi, hA_lo, W_hh, b_h, hB_hi, hB_lo, nullptr, nullptr);
  layer_kernel<HID, false, true><<<grd, blk, 0, stream>>>(
      nullptr, nullptr, hB_hi, hB_lo, W_hh, b_h, nullptr, nullptr, hp, hf);

  out_main<<<dim3(125 * KSPLIT), dim3(128), 0, stream>>>(hp, hf, W_hy, scratch);
  reduce_out<<<dim3(125, 64), dim3(256), 0, stream>>>(scratch, b_y, out);
}

// Round 16
// 136.595 us; speedup vs baseline: 3.7302x; 1.2277x over previous
//
#include <hip/hip_runtime.h>
#include <hip/hip_bf16.h>

#define BATCH 64
#define SEQT  512
#define EMB   1024
#define HID   2048
#define VOC   32000
#define KSPLIT 8

using bf16x8 = __attribute__((ext_vector_type(8))) __bf16;
using f32x4  = __attribute__((ext_vector_type(4))) float;

__device__ __forceinline__ void split2(float x, __bf16& hi, __bf16& lo) {
  hi = (__bf16)x;
  lo = (__bf16)(x - (float)hi);
}

// ---------------------------------------------------------------------------
// Layer kernel (round-9 verbatim, passing): h_out = tanh(A @ W + bias),
// split-bf16 (3 MFMA products), 16x16x32 MFMA, 256 blocks x 16 waves,
// LDS reduce. (PACKOUT path unused this round; all layers write planes.)
// ---------------------------------------------------------------------------
template <int KTOT, bool GATHER, bool PACKOUT>
__global__ __launch_bounds__(1024) void layer_kernel(
    const int* __restrict__ X, const float* __restrict__ emb,
    const __hip_bfloat16* __restrict__ hin_hi,
    const __hip_bfloat16* __restrict__ hin_lo,
    const float* __restrict__ W, const float* __restrict__ bias,
    __hip_bfloat16* __restrict__ hout_hi,
    __hip_bfloat16* __restrict__ hout_lo,
    unsigned* __restrict__ hp, float* __restrict__ hf) {
  constexpr int KCHUNK = KTOT / 16;   // 128 (HID) / 64 (EMB)
  constexpr int KSTEPS = KCHUNK / 32; // 4 / 2
  __shared__ float red[16 * 16 * 40];  // [wave][n][m_local pad 32->40]

  const int tid = threadIdx.x;
  const int w = tid >> 6;
  const int l = tid & 63;
  const int ln = l & 15;
  const int lg = l >> 4;
  const int n0 = (blockIdx.x & 127) * 16;
  const int mb = (blockIdx.x >> 7) * 32;  // M-half base

  f32x4 acc[2];
#pragma unroll
  for (int mt = 0; mt < 2; ++mt) acc[mt] = f32x4{0.f, 0.f, 0.f, 0.f};

  const float* grow[2];
#pragma unroll
  for (int mt = 0; mt < 2; ++mt) {
    if constexpr (GATHER) {
      const int m = mb + ln + 16 * mt;
      const int tok = X[m * SEQT + (SEQT - 1)];
      grow[mt] = emb + (size_t)tok * EMB;
    } else {
      grow[mt] = nullptr;
    }
  }

  const int kwave = w * KCHUNK + lg * 8;
  const float* Wc = W + n0 + ln;

  // hoist ALL W loads for this wave's K-chunk
  float wv[KSTEPS * 8];
#pragma unroll
  for (int j = 0; j < KSTEPS * 8; ++j)
    wv[j] = Wc[(size_t)(kwave + (j >> 3) * 32 + (j & 7)) * HID];

  // hoist ALL A fragments (split-bf16 planes)
  bf16x8 Ah[2][KSTEPS], Al[2][KSTEPS];
  if constexpr (GATHER) {
#pragma unroll
    for (int mt = 0; mt < 2; ++mt)
#pragma unroll
      for (int ks = 0; ks < KSTEPS; ++ks) {
        const float* p = grow[mt] + kwave + ks * 32;
        const f32x4 v0 = *reinterpret_cast<const f32x4*>(p);
        const f32x4 v1 = *reinterpret_cast<const f32x4*>(p + 4);
#pragma unroll
        for (int i = 0; i < 4; ++i) {
          __bf16 h_, l_;
          split2(v0[i], h_, l_);
          Ah[mt][ks][i] = h_;
          Al[mt][ks][i] = l_;
          split2(v1[i], h_, l_);
          Ah[mt][ks][4 + i] = h_;
          Al[mt][ks][4 + i] = l_;
        }
      }
  } else {
#pragma unroll
    for (int mt = 0; mt < 2; ++mt)
#pragma unroll
      for (int ks = 0; ks < KSTEPS; ++ks) {
        const size_t off = (size_t)(mb + ln + 16 * mt) * KTOT + kwave + ks * 32;
        Ah[mt][ks] = *reinterpret_cast<const bf16x8*>(hin_hi + off);
        Al[mt][ks] = *reinterpret_cast<const bf16x8*>(hin_lo + off);
      }
  }

#pragma unroll
  for (int ks = 0; ks < KSTEPS; ++ks) {
    bf16x8 bhi, blo;
#pragma unroll
    for (int i = 0; i < 8; ++i) {
      __bf16 h_, l_;
      split2(wv[ks * 8 + i], h_, l_);
      bhi[i] = h_;
      blo[i] = l_;
    }
#pragma unroll
    for (int mt = 0; mt < 2; ++mt) {
      acc[mt] = __builtin_amdgcn_mfma_f32_16x16x32_bf16(Ah[mt][ks], bhi, acc[mt], 0, 0, 0);
      acc[mt] = __builtin_amdgcn_mfma_f32_16x16x32_bf16(Al[mt][ks], bhi, acc[mt], 0, 0, 0);
      acc[mt] = __builtin_amdgcn_mfma_f32_16x16x32_bf16(Ah[mt][ks], blo, acc[mt], 0, 0, 0);
    }
  }

  // stash: red[(w*16+n)*40 + m_local]; acc[mt][j] -> m_local = mt*16+lg*4+j
  float* dst = &red[(w * 16 + ln) * 40 + lg * 4];
#pragma unroll
  for (int mt = 0; mt < 2; ++mt)
    *reinterpret_cast<f32x4*>(dst + mt * 16) = acc[mt];

  __syncthreads();

  if (tid < 512) {
    const int m = tid >> 4, n = tid & 15;  // m_local 0..31
    float s = 0.f;
#pragma unroll
    for (int ww = 0; ww < 16; ++ww) s += red[(ww * 16 + n) * 40 + m];
    s += bias[n0 + n];
    const float hval = tanhf(s);
    if constexpr (PACKOUT) {
      const int c = n0 + n;
      const int mg = mb + m;
      hf[(size_t)c * 64 + mg] = hval;
      const float partner = __shfl_xor(hval, 1, 64);
      if ((tid & 1) == 0) {
        using fp2 = __attribute__((ext_vector_type(2))) __fp16;
        const fp2 pk = __builtin_amdgcn_cvt_pkrtz(hval, partner);
        hp[(size_t)(c >> 1) * 64 + mg] = __builtin_bit_cast(unsigned, pk);
      }
    } else {
      __bf16 h_, l_;
      split2(hval, h_, l_);
      const size_t off = (size_t)(mb + m) * HID + (n0 + n);
      hout_hi[off] = *reinterpret_cast<__hip_bfloat16*>(&h_);
      hout_lo[off] = *reinterpret_cast<__hip_bfloat16*>(&l_);
    }
  }
}

// ---------------------------------------------------------------------------
// out_mfma: scratch[kq][m][n] = h[:, kq-slice] @ W_hy[kq-slice, :].
// Final layer has no tanh after it -> single-bf16 operands suffice
// (err ~0.2 << 5.02 threshold); hidden layers keep split-bf16.
// Structure: 2000 blocks = 8 kq x 250 nt; block = BN=128 cols, BK=256 k
// in 8 k-steps of 32. Per step: W tile [32k][128n] f32 reg-staged to LDS
// (r11-proven mechanics), DOUBLE-buffered 2x16 KB (total 32 KB -- every
// failing out-kernel had 64 KB LDS; passing ones <48 KB), issue-early /
// write-late (T14). Wave w owns cols [w*32, w*32+32): B-frags = 8x
// ds_read_b32 col-reads + cvt bf16 (4-way bank conflict = 1.58x, ~100cyc);
// A-frags = bf16x8 loads from L2-resident hA_hi, layer-kernel-verbatim
// fragment convention; 4x2 MFMA 16x16x32/step; acc full-K per wave ->
// direct scratch store (plain, round-8 poison lesson). 4-5 blocks/CU
// overlap across the 2-barrier steps (m114 cross-block overlap).
// ---------------------------------------------------------------------------
__global__ __launch_bounds__(256) void out_mfma(
    const __hip_bfloat16* __restrict__ hhi, const float* __restrict__ Why,
    float* __restrict__ scratch) {
  __shared__ float lds[2 * 32 * 128];  // 2 x 16 KB W tiles

  const int tid = threadIdx.x;
  const int w = tid >> 6;
  const int l = tid & 63;
  const int ln = l & 15;
  const int lg = l >> 4;
  const int nt = blockIdx.x % 250;
  const int kq = blockIdx.x / 250;
  const int n0 = nt * 128;
  const int k0 = kq * 256;

  // staging geometry: thread covers rows (tid>>5)+{0,8,16,24}, cols (tid&31)*4
  const int srow = tid >> 5;
  const int scol = (tid & 31) * 4;

  f32x4 acc[4][2];
#pragma unroll
  for (int mf = 0; mf < 4; ++mf)
#pragma unroll
    for (int nf = 0; nf < 2; ++nf) acc[mf][nf] = f32x4{0.f, 0.f, 0.f, 0.f};

  f32x4 st[4];

#define GLOAD(ks_)                                                           \
  {                                                                          \
    _Pragma("unroll") for (int i = 0; i < 4; ++i) {                          \
      st[i] = __builtin_nontemporal_load(reinterpret_cast<const f32x4*>(     \
          Why + (size_t)(k0 + (ks_) * 32 + srow + i * 8) * VOC + n0 + scol));\
    }                                                                        \
  }

#define DSWRITE(buf_)                                                        \
  {                                                                          \
    float* lb_ = lds + (buf_) * (32 * 128);                                  \
    _Pragma("unroll") for (int i = 0; i < 4; ++i) {                          \
      *reinterpret_cast<f32x4*>(lb_ + (srow + i * 8) * 128 + scol) = st[i];  \
    }                                                                        \
  }

#define COMPUTE(buf_, ks_)                                                   \
  {                                                                          \
    const float* lb_ = lds + (buf_) * (32 * 128);                            \
    bf16x8 a_[4];                                                            \
    _Pragma("unroll") for (int mf = 0; mf < 4; ++mf) {                       \
      a_[mf] = *reinterpret_cast<const bf16x8*>(                             \
          hhi + (size_t)(mf * 16 + ln) * HID + k0 + (ks_) * 32 + lg * 8);    \
    }                                                                        \
    bf16x8 b_[2];                                                            \
    _Pragma("unroll") for (int nf = 0; nf < 2; ++nf) {                       \
      _Pragma("unroll") for (int i = 0; i < 8; ++i) {                        \
        b_[nf][i] =                                                          \
            (__bf16)lb_[(lg * 8 + i) * 128 + w * 32 + nf * 16 + ln];         \
      }                                                                      \
    }                                                                        \
    _Pragma("unroll") for (int mf = 0; mf < 4; ++mf) {                       \
      _Pragma("unroll") for (int nf = 0; nf < 2; ++nf) {                     \
        acc[mf][nf] = __builtin_amdgcn_mfma_f32_16x16x32_bf16(               \
            a_[mf], b_[nf], acc[mf][nf], 0, 0, 0);                           \
      }                                                                      \
    }                                                                        \
  }

  // prologue
  GLOAD(0);
  DSWRITE(0);
  __syncthreads();

#pragma unroll
  for (int ks = 0; ks < 8; ++ks) {
    if (ks < 7) GLOAD(ks + 1);       // issue early: HBM latency hides here
    COMPUTE(ks & 1, ks);
    __syncthreads();                 // all waves done reading buf[(ks+1)&1]
    if (ks < 7) {
      DSWRITE((ks + 1) & 1);         // write late (loads have landed)
      __syncthreads();
    }
  }
#undef COMPUTE
#undef DSWRITE
#undef GLOAD

  // epilogue: C/D layout col=ln, row=lg*4+j (layer-kernel-verified).
  // PLAIN stores (kernel-to-kernel data through normal L2 path).
  float* sc = scratch + (size_t)kq * ((size_t)BATCH * VOC);
#pragma unroll
  for (int mf = 0; mf < 4; ++mf) {
#pragma unroll
    for (int nf = 0; nf < 2; ++nf) {
#pragma unroll
      for (int j = 0; j < 4; ++j) {
        const int row = mf * 16 + lg * 4 + j;
        const int col = n0 + w * 32 + nf * 16 + ln;
        sc[(size_t)row * VOC + col] = acc[mf][nf][j];
      }
    }
  }
}

// ---------------------------------------------------------------------------
// reduce_out: out[m][n] = sum_q scratch[q][m][n] + b_y[n].
// Grid (125, 64) x 256 thr; scratch is L2/L3-hot.
// ---------------------------------------------------------------------------
__global__ __launch_bounds__(256) void reduce_out(
    const float* __restrict__ scratch, const float* __restrict__ by,
    float* __restrict__ out) {
  const int n = blockIdx.x * 256 + threadIdx.x;
  const int m = blockIdx.y;
  float s = by[n];
#pragma unroll
  for (int q = 0; q < KSPLIT; ++q)
    s += scratch[(size_t)q * ((size_t)BATCH * VOC) + (size_t)m * VOC + n];
  __builtin_nontemporal_store(s, out + (size_t)m * VOC + n);
}

extern "C" void kernel_launch(void* const* d_in, const int* in_sizes, int n_in,
                              void* d_out, int out_size, void* d_ws,
                              size_t ws_size, hipStream_t stream) {
  const int* X = (const int*)d_in[0];
  const float* emb = (const float*)d_in[1];
  const float* W_xh = (const float*)d_in[2];
  const float* W_hh = (const float*)d_in[3];
  const float* W_hy = (const float*)d_in[4];
  const float* b_h = (const float*)d_in[5];
  const float* b_y = (const float*)d_in[6];
  float* out = (float*)d_out;

  char* ws = (char*)d_ws;
  const size_t PLANE = (size_t)BATCH * HID;  // elements
  __hip_bfloat16* hA_hi = (__hip_bfloat16*)ws;
  __hip_bfloat16* hA_lo = hA_hi + PLANE;
  __hip_bfloat16* hB_hi = hA_lo + PLANE;
  __hip_bfloat16* hB_lo = hB_hi + PLANE;
  float* scratch = (float*)(ws + 4 * PLANE * sizeof(__hip_bfloat16));
  // scratch: KSPLIT x 64 x 32000 f32 = 65.5 MB

  dim3 blk(1024), grd(256);
  layer_kernel<EMB, true, false><<<grd, blk, 0, stream>>>(
      X, emb, nullptr, nullptr, W_xh, b_h, hA_hi, hA_lo, nullptr, nullptr);
  layer_kernel<HID, false, false><<<grd, blk, 0, stream>>>(
      nullptr, nullptr, hA_hi, hA_lo, W_hh, b_h, hB_hi, hB_lo, nullptr, nullptr);
  layer_kernel<HID, false, false><<<grd, blk, 0, stream>>>(
      nullptr, nullptr, hB_hi, hB_lo, W_hh, b_h, hA_hi, hA_lo, nullptr, nullptr);
  layer_kernel<HID, false, false><<<grd, blk, 0, stream>>>(
      nullptr, nullptr, hA_hi, hA_lo, W_hh, b_h, hB_hi, hB_lo, nullptr, nullptr);
  layer_kernel<HID, false, false><<<grd, blk, 0, stream>>>(
      nullptr, nullptr, hB_hi, hB_lo, W_hh, b_h, hA_hi, hA_lo, nullptr, nullptr);

  out_mfma<<<dim3(2000), dim3(256), 0, stream>>>(hA_hi, W_hy, scratch);
  reduce_out<<<dim3(125, 64), dim3(256), 0, stream>>>(scratch, b_y, out);
}

// Round 17
// 126.300 us; speedup vs baseline: 4.0342x; 1.0815x over previous
//
#include <hip/hip_runtime.h>
#include <hip/hip_bf16.h>

#define BATCH 64
#define SEQT  512
#define EMB   1024
#define HID   2048
#define VOC   32000
#define KSPLIT 4

using bf16x8 = __attribute__((ext_vector_type(8))) __bf16;
using f32x4  = __attribute__((ext_vector_type(4))) float;

__device__ __forceinline__ void split2(float x, __bf16& hi, __bf16& lo) {
  hi = (__bf16)x;
  lo = (__bf16)(x - (float)hi);
}

// ---------------------------------------------------------------------------
// Layer kernel (round-9 verbatim, passing): h_out = tanh(A @ W + bias),
// split-bf16 (3 MFMA products), 16x16x32 MFMA, 256 blocks x 16 waves,
// LDS reduce.
// ---------------------------------------------------------------------------
template <int KTOT, bool GATHER>
__global__ __launch_bounds__(1024) void layer_kernel(
    const int* __restrict__ X, const float* __restrict__ emb,
    const __hip_bfloat16* __restrict__ hin_hi,
    const __hip_bfloat16* __restrict__ hin_lo,
    const float* __restrict__ W, const float* __restrict__ bias,
    __hip_bfloat16* __restrict__ hout_hi,
    __hip_bfloat16* __restrict__ hout_lo) {
  constexpr int KCHUNK = KTOT / 16;   // 128 (HID) / 64 (EMB)
  constexpr int KSTEPS = KCHUNK / 32; // 4 / 2
  __shared__ float red[16 * 16 * 40];  // [wave][n][m_local pad 32->40]

  const int tid = threadIdx.x;
  const int w = tid >> 6;
  const int l = tid & 63;
  const int ln = l & 15;
  const int lg = l >> 4;
  const int n0 = (blockIdx.x & 127) * 16;
  const int mb = (blockIdx.x >> 7) * 32;  // M-half base

  f32x4 acc[2];
#pragma unroll
  for (int mt = 0; mt < 2; ++mt) acc[mt] = f32x4{0.f, 0.f, 0.f, 0.f};

  const float* grow[2];
#pragma unroll
  for (int mt = 0; mt < 2; ++mt) {
    if constexpr (GATHER) {
      const int m = mb + ln + 16 * mt;
      const int tok = X[m * SEQT + (SEQT - 1)];
      grow[mt] = emb + (size_t)tok * EMB;
    } else {
      grow[mt] = nullptr;
    }
  }

  const int kwave = w * KCHUNK + lg * 8;
  const float* Wc = W + n0 + ln;

  // hoist ALL W loads for this wave's K-chunk
  float wv[KSTEPS * 8];
#pragma unroll
  for (int j = 0; j < KSTEPS * 8; ++j)
    wv[j] = Wc[(size_t)(kwave + (j >> 3) * 32 + (j & 7)) * HID];

  // hoist ALL A fragments (split-bf16 planes)
  bf16x8 Ah[2][KSTEPS], Al[2][KSTEPS];
  if constexpr (GATHER) {
#pragma unroll
    for (int mt = 0; mt < 2; ++mt)
#pragma unroll
      for (int ks = 0; ks < KSTEPS; ++ks) {
        const float* p = grow[mt] + kwave + ks * 32;
        const f32x4 v0 = *reinterpret_cast<const f32x4*>(p);
        const f32x4 v1 = *reinterpret_cast<const f32x4*>(p + 4);
#pragma unroll
        for (int i = 0; i < 4; ++i) {
          __bf16 h_, l_;
          split2(v0[i], h_, l_);
          Ah[mt][ks][i] = h_;
          Al[mt][ks][i] = l_;
          split2(v1[i], h_, l_);
          Ah[mt][ks][4 + i] = h_;
          Al[mt][ks][4 + i] = l_;
        }
      }
  } else {
#pragma unroll
    for (int mt = 0; mt < 2; ++mt)
#pragma unroll
      for (int ks = 0; ks < KSTEPS; ++ks) {
        const size_t off = (size_t)(mb + ln + 16 * mt) * KTOT + kwave + ks * 32;
        Ah[mt][ks] = *reinterpret_cast<const bf16x8*>(hin_hi + off);
        Al[mt][ks] = *reinterpret_cast<const bf16x8*>(hin_lo + off);
      }
  }

#pragma unroll
  for (int ks = 0; ks < KSTEPS; ++ks) {
    bf16x8 bhi, blo;
#pragma unroll
    for (int i = 0; i < 8; ++i) {
      __bf16 h_, l_;
      split2(wv[ks * 8 + i], h_, l_);
      bhi[i] = h_;
      blo[i] = l_;
    }
#pragma unroll
    for (int mt = 0; mt < 2; ++mt) {
      acc[mt] = __builtin_amdgcn_mfma_f32_16x16x32_bf16(Ah[mt][ks], bhi, acc[mt], 0, 0, 0);
      acc[mt] = __builtin_amdgcn_mfma_f32_16x16x32_bf16(Al[mt][ks], bhi, acc[mt], 0, 0, 0);
      acc[mt] = __builtin_amdgcn_mfma_f32_16x16x32_bf16(Ah[mt][ks], blo, acc[mt], 0, 0, 0);
    }
  }

  // stash: red[(w*16+n)*40 + m_local]; acc[mt][j] -> m_local = mt*16+lg*4+j
  float* dst = &red[(w * 16 + ln) * 40 + lg * 4];
#pragma unroll
  for (int mt = 0; mt < 2; ++mt)
    *reinterpret_cast<f32x4*>(dst + mt * 16) = acc[mt];

  __syncthreads();

  if (tid < 512) {
    const int m = tid >> 4, n = tid & 15;  // m_local 0..31
    float s = 0.f;
#pragma unroll
    for (int ww = 0; ww < 16; ++ww) s += red[(ww * 16 + n) * 40 + m];
    s += bias[n0 + n];
    const float hval = tanhf(s);
    __bf16 h_, l_;
    split2(hval, h_, l_);
    const size_t off = (size_t)(mb + m) * HID + (n0 + n);
    hout_hi[off] = *reinterpret_cast<__hip_bfloat16*>(&h_);
    hout_lo[off] = *reinterpret_cast<__hip_bfloat16*>(&l_);
  }
}

// ---------------------------------------------------------------------------
// out_mfma v2: scratch[kq][m][n] = h[:, kq-slice] @ W_hy[kq-slice, :].
// r16 (passing, ~84us) upgraded: TRIPLE-buffered LDS (3x16KB=48KB,
// r5-proven size) + 2-step-ahead load issue + ONE barrier per step.
// Iter ks: GLOAD(ks+2, set(ks&1)) | DSWRITE(ks+1, buf((ks+1)%3),
// set((ks+1)&1)) | COMPUTE(buf(ks%3), ks) | barrier.
// Safety: buf((ks+1)%3) last read at COMPUTE(ks-2) (sealed 2 barriers ago);
// reg sets alternate with disjoint lifetimes; all indices compile-time
// (full unroll, rule #20). DSWRITE's vmcnt wait lands on loads issued a
// full iteration (~900cyc) earlier instead of ~220cyc.
// KSPLIT 8->4 (BK=512, 16 steps): scratch round-trip 131->66 MB.
// Single-bf16 operands (final layer, no tanh amplification after).
// Grid: 1000 blocks = 4 kq x 250 nt; 3 blocks/CU (48KB LDS).
// ---------------------------------------------------------------------------
__global__ __launch_bounds__(256) void out_mfma(
    const __hip_bfloat16* __restrict__ hhi, const float* __restrict__ Why,
    float* __restrict__ scratch) {
  __shared__ float lds[3 * 32 * 128];  // 3 x 16 KB W tiles

  const int tid = threadIdx.x;
  const int w = tid >> 6;
  const int l = tid & 63;
  const int ln = l & 15;
  const int lg = l >> 4;
  const int nt = blockIdx.x % 250;
  const int kq = blockIdx.x / 250;
  const int n0 = nt * 128;
  const int k0 = kq * 512;
  constexpr int NS = 16;  // k-steps of 32

  // staging geometry: thread covers rows (tid>>5)+{0,8,16,24}, cols (tid&31)*4
  const int srow = tid >> 5;
  const int scol = (tid & 31) * 4;

  f32x4 acc[4][2];
#pragma unroll
  for (int mf = 0; mf < 4; ++mf)
#pragma unroll
    for (int nf = 0; nf < 2; ++nf) acc[mf][nf] = f32x4{0.f, 0.f, 0.f, 0.f};

  f32x4 stA[4], stB[4];

#define GLOAD(ks_, st_)                                                      \
  {                                                                          \
    _Pragma("unroll") for (int i = 0; i < 4; ++i) {                          \
      st_[i] = __builtin_nontemporal_load(reinterpret_cast<const f32x4*>(    \
          Why + (size_t)(k0 + (ks_) * 32 + srow + i * 8) * VOC + n0 + scol));\
    }                                                                        \
  }

#define DSWRITE(buf_, st_)                                                   \
  {                                                                          \
    float* lb_ = lds + (buf_) * (32 * 128);                                  \
    _Pragma("unroll") for (int i = 0; i < 4; ++i) {                          \
      *reinterpret_cast<f32x4*>(lb_ + (srow + i * 8) * 128 + scol) = st_[i]; \
    }                                                                        \
  }

#define COMPUTE(buf_, ks_)                                                   \
  {                                                                          \
    const float* lb_ = lds + (buf_) * (32 * 128);                            \
    bf16x8 a_[4];                                                            \
    _Pragma("unroll") for (int mf = 0; mf < 4; ++mf) {                       \
      a_[mf] = *reinterpret_cast<const bf16x8*>(                             \
          hhi + (size_t)(mf * 16 + ln) * HID + k0 + (ks_) * 32 + lg * 8);    \
    }                                                                        \
    bf16x8 b_[2];                                                            \
    _Pragma("unroll") for (int nf = 0; nf < 2; ++nf) {                       \
      _Pragma("unroll") for (int i = 0; i < 8; ++i) {                        \
        b_[nf][i] =                                                          \
            (__bf16)lb_[(lg * 8 + i) * 128 + w * 32 + nf * 16 + ln];         \
      }                                                                      \
    }                                                                        \
    _Pragma("unroll") for (int mf = 0; mf < 4; ++mf) {                       \
      _Pragma("unroll") for (int nf = 0; nf < 2; ++nf) {                     \
        acc[mf][nf] = __builtin_amdgcn_mfma_f32_16x16x32_bf16(               \
            a_[mf], b_[nf], acc[mf][nf], 0, 0, 0);                           \
      }                                                                      \
    }                                                                        \
  }

  // prologue: step0 staged+written, step1 in flight
  GLOAD(0, stA);
  DSWRITE(0, stA);
  GLOAD(1, stB);
  __syncthreads();

#pragma unroll
  for (int ks = 0; ks < NS; ++ks) {
    // issue 2 ahead into the set whose data was consumed at iter ks-1
    if (ks + 2 < NS) {
      if ((ks & 1) == 0) GLOAD(ks + 2, stA) else GLOAD(ks + 2, stB);
    }
    // write 1 ahead from the set loaded at iter ks-1 (vmcnt cover ~1 iter)
    if (ks + 1 < NS) {
      if (((ks + 1) & 1) == 0) DSWRITE((ks + 1) % 3, stA)
      else DSWRITE((ks + 1) % 3, stB);
    }
    COMPUTE(ks % 3, ks);
    if (ks + 1 < NS) __syncthreads();
  }
#undef COMPUTE
#undef DSWRITE
#undef GLOAD

  // epilogue: C/D layout col=ln, row=lg*4+j (layer-kernel-verified).
  // PLAIN stores (kernel-to-kernel data through normal L2 path).
  float* sc = scratch + (size_t)kq * ((size_t)BATCH * VOC);
#pragma unroll
  for (int mf = 0; mf < 4; ++mf) {
#pragma unroll
    for (int nf = 0; nf < 2; ++nf) {
#pragma unroll
      for (int j = 0; j < 4; ++j) {
        const int row = mf * 16 + lg * 4 + j;
        const int col = n0 + w * 32 + nf * 16 + ln;
        sc[(size_t)row * VOC + col] = acc[mf][nf][j];
      }
    }
  }
}

// ---------------------------------------------------------------------------
// reduce_out: out[m][n] = sum_q scratch[q][m][n] + b_y[n].
// Grid (125, 64) x 256 thr; scratch is L2/L3-hot.
// ---------------------------------------------------------------------------
__global__ __launch_bounds__(256) void reduce_out(
    const float* __restrict__ scratch, const float* __restrict__ by,
    float* __restrict__ out) {
  const int n = blockIdx.x * 256 + threadIdx.x;
  const int m = blockIdx.y;
  float s = by[n];
#pragma unroll
  for (int q = 0; q < KSPLIT; ++q)
    s += scratch[(size_t)q * ((size_t)BATCH * VOC) + (size_t)m * VOC + n];
  __builtin_nontemporal_store(s, out + (size_t)m * VOC + n);
}

extern "C" void kernel_launch(void* const* d_in, const int* in_sizes, int n_in,
                              void* d_out, int out_size, void* d_ws,
                              size_t ws_size, hipStream_t stream) {
  const int* X = (const int*)d_in[0];
  const float* emb = (const float*)d_in[1];
  const float* W_xh = (const float*)d_in[2];
  const float* W_hh = (const float*)d_in[3];
  const float* W_hy = (const float*)d_in[4];
  const float* b_h = (const float*)d_in[5];
  const float* b_y = (const float*)d_in[6];
  float* out = (float*)d_out;

  char* ws = (char*)d_ws;
  const size_t PLANE = (size_t)BATCH * HID;  // elements
  __hip_bfloat16* hA_hi = (__hip_bfloat16*)ws;
  __hip_bfloat16* hA_lo = hA_hi + PLANE;
  __hip_bfloat16* hB_hi = hA_lo + PLANE;
  __hip_bfloat16* hB_lo = hB_hi + PLANE;
  float* scratch = (float*)(ws + 4 * PLANE * sizeof(__hip_bfloat16));
  // scratch: KSPLIT(4) x 64 x 32000 f32 = 32.8 MB

  dim3 blk(1024), grd(256);
  layer_kernel<EMB, true><<<grd, blk, 0, stream>>>(
      X, emb, nullptr, nullptr, W_xh, b_h, hA_hi, hA_lo);
  layer_kernel<HID, false><<<grd, blk, 0, stream>>>(
      nullptr, nullptr, hA_hi, hA_lo, W_hh, b_h, hB_hi, hB_lo);
  layer_kernel<HID, false><<<grd, blk, 0, stream>>>(
      nullptr, nullptr, hB_hi, hB_lo, W_hh, b_h, hA_hi, hA_lo);
  layer_kernel<HID, false><<<grd, blk, 0, stream>>>(
      nullptr, nullptr, hA_hi, hA_lo, W_hh, b_h, hB_hi, hB_lo);
  layer_kernel<HID, false><<<grd, blk, 0, stream>>>(
      nullptr, nullptr, hB_hi, hB_lo, W_hh, b_h, hA_hi, hA_lo);

  out_mfma<<<dim3(1000), dim3(256), 0, stream>>>(hA_hi, W_hy, scratch);
  reduce_out<<<dim3(125, 64), dim3(256), 0, stream>>>(scratch, b_y, out);
}